// Round 8
// baseline (7232.842 us; speedup 1.0000x reference)
//
#include <hip/hip_runtime.h>
#include <cmath>

// Problem constants: B=16, T=512, S=320, H=512, K=1024, NQ=4, M=B*T=8192

// ---------------- generic 64x64 tile f32 GEMM (small-N ops) ----------------
template<bool BT>
__global__ __launch_bounds__(256)
void gemm64(const float* __restrict__ A, const float* __restrict__ B,
            float* __restrict__ C, int M, int N, int K,
            const float* __restrict__ bias1, const float* __restrict__ bias2)
{
    __shared__ float Al[32][68];
    __shared__ float Bl[32][68];
    const int m0 = blockIdx.y * 64, n0 = blockIdx.x * 64;
    const int t = threadIdx.x;
    const int tm = t >> 4, tn = t & 15;
    float acc[4][4] = {{0.f, 0.f, 0.f, 0.f}};

    for (int k0 = 0; k0 < K; k0 += 32) {
        #pragma unroll
        for (int i = 0; i < 2; i++) {
            int f4 = t + i * 256;
            int row = f4 >> 3, c4 = f4 & 7;
            float4 v = *(const float4*)(A + (size_t)(m0 + row) * K + k0 + c4 * 4);
            Al[c4*4+0][row] = v.x; Al[c4*4+1][row] = v.y;
            Al[c4*4+2][row] = v.z; Al[c4*4+3][row] = v.w;
        }
        if (BT) {
            #pragma unroll
            for (int i = 0; i < 2; i++) {
                int f4 = t + i * 256;
                int row = f4 >> 3, c4 = f4 & 7;
                float4 v = *(const float4*)(B + (size_t)(n0 + row) * K + k0 + c4 * 4);
                Bl[c4*4+0][row] = v.x; Bl[c4*4+1][row] = v.y;
                Bl[c4*4+2][row] = v.z; Bl[c4*4+3][row] = v.w;
            }
        } else {
            #pragma unroll
            for (int i = 0; i < 2; i++) {
                int f4 = t + i * 256;
                int kk = f4 >> 4, c4 = f4 & 15;
                float4 v = *(const float4*)(B + (size_t)(k0 + kk) * N + n0 + c4 * 4);
                *(float4*)&Bl[kk][c4 * 4] = v;
            }
        }
        __syncthreads();
        #pragma unroll
        for (int k = 0; k < 32; k++) {
            float4 a4 = *(const float4*)&Al[k][tm * 4];
            float4 b4 = *(const float4*)&Bl[k][tn * 4];
            float av[4] = {a4.x, a4.y, a4.z, a4.w};
            float bv[4] = {b4.x, b4.y, b4.z, b4.w};
            #pragma unroll
            for (int i = 0; i < 4; i++)
                #pragma unroll
                for (int j = 0; j < 4; j++)
                    acc[i][j] = fmaf(av[i], bv[j], acc[i][j]);
        }
        __syncthreads();
    }
    float bn[4];
    #pragma unroll
    for (int j = 0; j < 4; j++) {
        float bb = 0.f;
        if (bias1) bb += bias1[n0 + tn * 4 + j];
        if (bias2) bb += bias2[n0 + tn * 4 + j];
        bn[j] = bb;
    }
    #pragma unroll
    for (int i = 0; i < 4; i++) {
        float4 o;
        o.x = acc[i][0] + bn[0]; o.y = acc[i][1] + bn[1];
        o.z = acc[i][2] + bn[2]; o.w = acc[i][3] + bn[3];
        *(float4*)(C + (size_t)(m0 + tm * 4 + i) * N + n0 + tn * 4) = o;
    }
}

// ---------------- 128x128 tile f32 GEMM, 8x8 acc (VQ distances, P1) ----------------
template<bool BT>
__global__ __launch_bounds__(256)
void gemm128(const float* __restrict__ A, const float* __restrict__ B,
             float* __restrict__ C, int M, int N, int K,
             const float* __restrict__ bias1, const float* __restrict__ bias2)
{
    __shared__ float Al[16][132];
    __shared__ float Bl[16][132];
    const int m0 = blockIdx.y * 128, n0 = blockIdx.x * 128;
    const int t = threadIdx.x;
    const int tm = t >> 4, tn = t & 15;
    float acc[8][8] = {};

    for (int k0 = 0; k0 < K; k0 += 16) {
        #pragma unroll
        for (int i = 0; i < 2; i++) {
            int f4 = t + i * 256;              // 0..511
            int row = f4 >> 2, c4 = f4 & 3;
            float4 v = *(const float4*)(A + (size_t)(m0 + row) * K + k0 + c4 * 4);
            Al[c4*4+0][row] = v.x; Al[c4*4+1][row] = v.y;
            Al[c4*4+2][row] = v.z; Al[c4*4+3][row] = v.w;
        }
        if (BT) {
            #pragma unroll
            for (int i = 0; i < 2; i++) {
                int f4 = t + i * 256;
                int row = f4 >> 2, c4 = f4 & 3;
                float4 v = *(const float4*)(B + (size_t)(n0 + row) * K + k0 + c4 * 4);
                Bl[c4*4+0][row] = v.x; Bl[c4*4+1][row] = v.y;
                Bl[c4*4+2][row] = v.z; Bl[c4*4+3][row] = v.w;
            }
        } else {
            #pragma unroll
            for (int i = 0; i < 2; i++) {
                int f4 = t + i * 256;
                int kk = f4 >> 5, c4 = f4 & 31;
                float4 v = *(const float4*)(B + (size_t)(k0 + kk) * N + n0 + c4 * 4);
                *(float4*)&Bl[kk][c4 * 4] = v;
            }
        }
        __syncthreads();
        #pragma unroll
        for (int k = 0; k < 16; k++) {
            float4 a0 = *(const float4*)&Al[k][tm * 8];
            float4 a1 = *(const float4*)&Al[k][tm * 8 + 4];
            float4 b0 = *(const float4*)&Bl[k][tn * 8];
            float4 b1 = *(const float4*)&Bl[k][tn * 8 + 4];
            float av[8] = {a0.x,a0.y,a0.z,a0.w,a1.x,a1.y,a1.z,a1.w};
            float bv[8] = {b0.x,b0.y,b0.z,b0.w,b1.x,b1.y,b1.z,b1.w};
            #pragma unroll
            for (int i = 0; i < 8; i++)
                #pragma unroll
                for (int j = 0; j < 8; j++)
                    acc[i][j] = fmaf(av[i], bv[j], acc[i][j]);
        }
        __syncthreads();
    }
    float bn[8];
    #pragma unroll
    for (int j = 0; j < 8; j++) {
        float bb = 0.f;
        if (bias1) bb += bias1[n0 + tn * 8 + j];
        if (bias2) bb += bias2[n0 + tn * 8 + j];
        bn[j] = bb;
    }
    #pragma unroll
    for (int i = 0; i < 8; i++) {
        float* cp = C + (size_t)(m0 + tm * 8 + i) * N + n0 + tn * 8;
        float4 o0, o1;
        o0.x = acc[i][0]+bn[0]; o0.y = acc[i][1]+bn[1];
        o0.z = acc[i][2]+bn[2]; o0.w = acc[i][3]+bn[3];
        o1.x = acc[i][4]+bn[4]; o1.y = acc[i][5]+bn[5];
        o1.z = acc[i][6]+bn[6]; o1.w = acc[i][7]+bn[7];
        *(float4*)cp = o0;
        *(float4*)(cp + 4) = o1;
    }
}

// ---------------- LayerNorm + ReLU in place ----------------
__global__ __launch_bounds__(256)
void ln_relu_kernel(float* __restrict__ X, const float* __restrict__ g,
                    const float* __restrict__ bb)
{
    __shared__ float red[256];
    __shared__ float stat[2];
    const int row = blockIdx.x, t = threadIdx.x;
    float x0 = X[(size_t)row * 512 + t];
    float x1 = X[(size_t)row * 512 + 256 + t];
    red[t] = x0 + x1;
    __syncthreads();
    for (int o = 128; o > 0; o >>= 1) { if (t < o) red[t] += red[t + o]; __syncthreads(); }
    if (t == 0) stat[0] = red[0] * (1.f / 512.f);
    __syncthreads();
    float mu = stat[0];
    float d0 = x0 - mu, d1 = x1 - mu;
    red[t] = d0 * d0 + d1 * d1;
    __syncthreads();
    for (int o = 128; o > 0; o >>= 1) { if (t < o) red[t] += red[t + o]; __syncthreads(); }
    if (t == 0) stat[1] = red[0] * (1.f / 512.f);
    __syncthreads();
    float rs = rsqrtf(stat[1] + 1e-5f);
    float y0 = d0 * rs * g[t] + bb[t];
    float y1 = d1 * rs * g[256 + t] + bb[256 + t];
    X[(size_t)row * 512 + t] = fmaxf(y0, 0.f);
    X[(size_t)row * 512 + 256 + t] = fmaxf(y1, 0.f);
}

// ---------------- codebook row squared-norms ----------------
__global__ __launch_bounds__(256)
void rownorm_kernel(const float* __restrict__ Ein, float* __restrict__ norms)
{
    __shared__ float red[256];
    const int row = blockIdx.x, t = threadIdx.x;
    float a = Ein[(size_t)row * 512 + t];
    float b = Ein[(size_t)row * 512 + 256 + t];
    red[t] = a * a + b * b;
    __syncthreads();
    for (int o = 128; o > 0; o >>= 1) { if (t < o) red[t] += red[t + o]; __syncthreads(); }
    if (t == 0) norms[row] = red[0];
}

// ---------------- VQ argmin + STE update ----------------
// quant written ROW-PERMUTED (tokP = s*16 + b) so the P1 GEMM produces P1 in
// step-major layout (row m' = s*16 + b); LSTM reads contiguous per-step windows.
__global__ __launch_bounds__(256)
void vq_update_kernel(const float* __restrict__ D, const float* __restrict__ norms,
                      const float* __restrict__ cb, float* __restrict__ residual,
                      float* __restrict__ quant, float* __restrict__ loss_acc,
                      int first)
{
    __shared__ unsigned long long red[256];
    __shared__ float fred[256];
    __shared__ int sidx;
    __shared__ float sdmin;
    const int tok = blockIdx.x, t = threadIdx.x;
    unsigned long long best = ~0ull;
    #pragma unroll
    for (int i = 0; i < 4; i++) {
        int k = t + i * 256;
        float d = fmaf(-2.f, D[(size_t)tok * 1024 + k], norms[k]);
        unsigned u = __float_as_uint(d);
        u = (u & 0x80000000u) ? ~u : (u | 0x80000000u);
        unsigned long long p = ((unsigned long long)u << 32) | (unsigned)k;
        best = p < best ? p : best;
    }
    red[t] = best;
    __syncthreads();
    for (int o = 128; o > 0; o >>= 1) {
        if (t < o) red[t] = red[t + o] < red[t] ? red[t + o] : red[t];
        __syncthreads();
    }
    if (t == 0) {
        unsigned long long r0 = red[0];
        sidx = (int)(r0 & 0xffffffffu);
        unsigned uv = (unsigned)(r0 >> 32);
        unsigned orig = (uv & 0x80000000u) ? (uv ^ 0x80000000u) : ~uv;
        sdmin = __uint_as_float(orig);
    }
    float r0v = residual[(size_t)tok * 512 + t];
    float r1v = residual[(size_t)tok * 512 + 256 + t];
    fred[t] = r0v * r0v + r1v * r1v;
    __syncthreads();
    for (int o = 128; o > 0; o >>= 1) { if (t < o) fred[t] += fred[t + o]; __syncthreads(); }
    int idx = sidx;
    if (t == 0) atomicAdd(loss_acc, sdmin + fred[0]);
    const float* E = cb + (size_t)idx * 512;
    float e0 = E[t], e1 = E[256 + t];
    float q0 = r0v + (e0 - r0v);
    float q1 = r1v + (e1 - r1v);
    residual[(size_t)tok * 512 + t]       = r0v - q0;
    residual[(size_t)tok * 512 + 256 + t] = r1v - q1;
    const int tokP = ((tok & 511) << 4) | (tok >> 9);   // s*16 + b
    if (first) {
        quant[(size_t)tokP * 512 + t]       = q0;
        quant[(size_t)tokP * 512 + 256 + t] = q1;
    } else {
        quant[(size_t)tokP * 512 + t]       += q0;
        quant[(size_t)tokP * 512 + 256 + t] += q1;
    }
}

// ================= fused 2-layer LSTM ==============================================
// R8 (measured R7: step=10.0us; sync-mechanism changes R2/R5/R6/R7 all neutral ->
// sync is not the pole; VALU=1.8us; largest unattacked term = LDS-read ISSUE in
// the dot phase: role-1 issued 256 ds_read_b128/thread, ~12cyc each).
// Change: (b8,cl2) work mapping — each thread covers 2 adjacent cols x 8 batch
// rows (was 1 col x 16 rows). Each ds_read_b128 now feeds 8 FMAs (was 4):
// role-0 64 reads/thread (was 128), role-1 128 (was 256). Costs +32/+64 weight
// VGPRs (1 block/CU -> budget fine). Reduce/gl/gate phases unchanged.

#define LSTRIDE 137          // float4 stride per sample row in LDS (16 rows)
#define SLOT_STRIDE 16       // u32 stride between slots = 64B = 1 line

__device__ __forceinline__ void wait_vm0() {
    asm volatile("s_waitcnt vmcnt(0)" ::: "memory");
}

__device__ __forceinline__ void ld4_issue(float4& a, float4& b, float4& c, float4& d,
                                          const float4* p0, const float4* p1,
                                          const float4* p2, const float4* p3)
{
    asm volatile(
        "global_load_dwordx4 %0, %4, off sc0 sc1\n\t"
        "global_load_dwordx4 %1, %5, off sc0 sc1\n\t"
        "global_load_dwordx4 %2, %6, off sc0 sc1\n\t"
        "global_load_dwordx4 %3, %7, off sc0 sc1"
        : "=&v"(a), "=&v"(b), "=&v"(c), "=&v"(d)
        : "v"(p0), "v"(p1), "v"(p2), "v"(p3)
        : "memory");
}

// stage 32KB block-major global h -> transposed/swizzled LDS, ONE drain
__device__ __forceinline__ void stage8t(float4* d4, const float* src, int t)
{
    const float4* s4 = (const float4*)src;
    float4 v[8];
    ld4_issue(v[0], v[1], v[2], v[3], s4 + t, s4 + t + 256, s4 + t + 512, s4 + t + 768);
    ld4_issue(v[4], v[5], v[6], v[7], s4 + t + 1024, s4 + t + 1280, s4 + t + 1536, s4 + t + 1792);
    wait_vm0();
    #pragma unroll
    for (int i = 0; i < 8; i++) {
        int G = t + i * 256;
        int b = G & 15, blk = G >> 4;              // blk = ks*8 + pp
        d4[b * LSTRIDE + (blk & 7) * 17 + (blk >> 3)] = v[i];
    }
}

// stage 2x32KB with 16 loads in flight, ONE drain (role-1 x + h)
__device__ __forceinline__ void stage16t(float4* d1, const float* src1,
                                         float4* d2, const float* src2, int t)
{
    const float4* s1 = (const float4*)src1;
    const float4* s2 = (const float4*)src2;
    float4 v[16];
    ld4_issue(v[0], v[1], v[2], v[3],  s1 + t, s1 + t + 256, s1 + t + 512, s1 + t + 768);
    ld4_issue(v[4], v[5], v[6], v[7],  s1 + t + 1024, s1 + t + 1280, s1 + t + 1536, s1 + t + 1792);
    ld4_issue(v[8], v[9], v[10],v[11], s2 + t, s2 + t + 256, s2 + t + 512, s2 + t + 768);
    ld4_issue(v[12],v[13],v[14],v[15], s2 + t + 1024, s2 + t + 1280, s2 + t + 1536, s2 + t + 1792);
    wait_vm0();
    #pragma unroll
    for (int i = 0; i < 8; i++) {
        int G = t + i * 256;
        int b = G & 15, blk = G >> 4;
        int idx = b * LSTRIDE + (blk & 7) * 17 + (blk >> 3);
        d1[idx] = v[i];
        d2[idx] = v[i + 8];
    }
}

__device__ __forceinline__ unsigned slot_load(const unsigned* p)
{
    return __hip_atomic_load(p, __ATOMIC_RELAXED, __HIP_MEMORY_SCOPE_AGENT);
}

// one wave checks all 128 slots (2 loads/lane)
__device__ __forceinline__ void poll128(const unsigned* slots, int lane, unsigned tgt)
{
    const unsigned* p0 = slots + (size_t)lane * SLOT_STRIDE;
    const unsigned* p1 = slots + (size_t)(64 + lane) * SLOT_STRIDE;
    int spins = 0;
    while (true) {
        unsigned a = slot_load(p0);
        unsigned b = slot_load(p1);
        if (__all(a >= tgt && b >= tgt)) break;
        __builtin_amdgcn_s_sleep(2);
        if (++spins > 300000) break;   // bounded: never hang
    }
}

__global__ __launch_bounds__(256, 1)
void lstm_fused_kernel(const float* __restrict__ P1,   // step-major rows: m' = s*16+b
                       const float* __restrict__ wh1,
                       const float* __restrict__ wi2,
                       const float* __restrict__ wh2,
                       const float* __restrict__ bi2,
                       const float* __restrict__ bh2,
                       float* __restrict__ H2out,
                       float* __restrict__ h1hist,   // [step][block][64]
                       float* __restrict__ h2hist,   // [step][block][64]
                       unsigned* __restrict__ slots)
{
    __shared__ float4 hl4[16 * LSTRIDE];   // 34.25 KB x-staging (swizzled)
    __shared__ float4 hl24[16 * LSTRIDE];  // 34.25 KB h-staging (role 1)
    __shared__ float part[16 * 256];       // 16 KB partials
    __shared__ float gl[256];
    __shared__ float c_lds[64];

    const int t = threadIdx.x;
    const int role = blockIdx.x >> 7;
    const int bid = blockIdx.x & 127;
    const int ks = t >> 4;                 // 0..15 k-slice
    const int q  = t & 15;
    const int cp = q >> 1;                 // 0..7 column pair
    const int bh = q & 1;                  // batch half (b = bh*8 + i)
    const int c0 = cp * 2;                 // block-local cols c0, c0+1
    const int j_base = bid * 4;
    const int cl_r = t >> 4, b_r = t & 15;
    const int gate_r = cl_r >> 2, jj_r = cl_r & 3;
    const int w = t >> 6, lane = t & 63;

    unsigned* slots0 = slots;
    unsigned* slots1 = slots + 128 * SLOT_STRIDE;

    // weights for the two adjacent columns (same gate, adjacent jj since c0 even)
    float wh0[32], wh1r[32], wx0[32], wx1[32];
    {
        const float* whp = (role == 0) ? wh1 : wh2;
        const int gate0 = c0 >> 2, jj0 = c0 & 3;
        const float* wr = whp + (size_t)(gate0 * 512 + j_base + jj0) * 512 + ks * 32;
        #pragma unroll
        for (int i = 0; i < 32; i++) { wh0[i] = wr[i]; wh1r[i] = wr[512 + i]; }
    }
    if (role == 1) {
        const int gate0 = c0 >> 2, jj0 = c0 & 3;
        const float* wr = wi2 + (size_t)(gate0 * 512 + j_base + jj0) * 512 + ks * 32;
        #pragma unroll
        for (int i = 0; i < 32; i++) { wx0[i] = wr[i]; wx1[i] = wr[512 + i]; }
    } else {
        #pragma unroll
        for (int i = 0; i < 32; i++) { wx0[i] = 0.f; wx1[i] = 0.f; }
    }
    float bias2v = 0.f;
    if (role == 1) {
        int col = gate_r * 512 + j_base + jj_r;
        bias2v = bi2[col] + bh2[col];
    }
    if (t < 64) c_lds[t] = 0.f;

    if (role == 0) {
        // -------- layer 1: 128 blocks, peer slot-barrier only (wave 0 polls)
        const float* pvp = P1 + (size_t)b_r * 2048 + gate_r * 512 + j_base + jj_r;
        float pv = pvp[0];                       // step 0 row = 0*16 + b_r
        for (int s = 0; s < 512; s++) {
            if (w == 0) poll128(slots0, lane, (unsigned)s);
            __syncthreads();
            if (s > 0) {
                stage8t(hl4, h1hist + (size_t)(s - 1) * 8192, t);
            } else {
                float4 z = make_float4(0.f, 0.f, 0.f, 0.f);
                #pragma unroll
                for (int i = 0; i < 9; i++) {
                    int idx = t + i * 256;
                    if (idx < 16 * LSTRIDE) hl4[idx] = z;
                }
            }
            // prefetch next step's P1 (contiguous step-major window)
            float pv_next = (s < 511) ? pvp[(size_t)(s + 1) * 32768] : 0.f;
            __syncthreads();
            float acc0[8], acc1[8];
            #pragma unroll
            for (int i = 0; i < 8; i++) { acc0[i] = 0.f; acc1[i] = 0.f; }
            #pragma unroll
            for (int i = 0; i < 8; i++) {
                const float4* hrow = hl4 + (bh * 8 + i) * LSTRIDE + ks;
                #pragma unroll
                for (int pp = 0; pp < 8; pp++) {
                    float4 h4 = hrow[pp * 17];
                    acc0[i] = fmaf(h4.x, wh0[pp*4+0], acc0[i]);
                    acc1[i] = fmaf(h4.x, wh1r[pp*4+0], acc1[i]);
                    acc0[i] = fmaf(h4.y, wh0[pp*4+1], acc0[i]);
                    acc1[i] = fmaf(h4.y, wh1r[pp*4+1], acc1[i]);
                    acc0[i] = fmaf(h4.z, wh0[pp*4+2], acc0[i]);
                    acc1[i] = fmaf(h4.z, wh1r[pp*4+2], acc1[i]);
                    acc0[i] = fmaf(h4.w, wh0[pp*4+3], acc0[i]);
                    acc1[i] = fmaf(h4.w, wh1r[pp*4+3], acc1[i]);
                }
            }
            #pragma unroll
            for (int i = 0; i < 8; i++) {
                part[ks * 256 + c0 * 16 + bh * 8 + i]       = acc0[i];
                part[ks * 256 + (c0 + 1) * 16 + bh * 8 + i] = acc1[i];
            }
            __syncthreads();
            float gv = pv;
            #pragma unroll
            for (int k = 0; k < 16; k++)
                gv += part[k * 256 + cl_r * 16 + b_r];
            gl[cl_r * 16 + b_r] = gv;
            __syncthreads();
            if (t < 64) {
                int b = t >> 2, jr = t & 3;
                float iv = gl[(0 + jr) * 16 + b];
                float fv = gl[(4 + jr) * 16 + b];
                float gg = gl[(8 + jr) * 16 + b];
                float ov = gl[(12 + jr) * 16 + b];
                float ig = 1.f / (1.f + expf(-iv));
                float fg = 1.f / (1.f + expf(-fv));
                float og = 1.f / (1.f + expf(-ov));
                float cn = fg * c_lds[t] + ig * tanhf(gg);
                float hn = og * tanhf(cn);
                c_lds[t] = cn;
                __hip_atomic_store(&h1hist[(size_t)s * 8192 + bid * 64 + t], hn,
                                   __ATOMIC_RELAXED, __HIP_MEMORY_SCOPE_AGENT);
            }
            wait_vm0();                 // t==0 is in wave 0: drains all t<64 stores
            if (t == 0)
                __hip_atomic_store(&slots0[bid * SLOT_STRIDE], (unsigned)(s + 1),
                                   __ATOMIC_RELAXED, __HIP_MEMORY_SCOPE_AGENT);
            pv = pv_next;
        }
    } else {
        // -------- layer 2: wave0 polls h1-ready, wave1 polls peers-done, concurrently
        for (int m = 0; m < 512; m++) {
            if (w == 0)      poll128(slots0, lane, (unsigned)(m + 1));
            else if (w == 1) poll128(slots1, lane, (unsigned)m);
            __syncthreads();
            if (m > 0) {
                stage16t(hl4, h1hist + (size_t)m * 8192,
                         hl24, h2hist + (size_t)(m - 1) * 8192, t);
            } else {
                stage8t(hl4, h1hist, t);
                float4 z = make_float4(0.f, 0.f, 0.f, 0.f);
                #pragma unroll
                for (int i = 0; i < 9; i++) {
                    int idx = t + i * 256;
                    if (idx < 16 * LSTRIDE) hl24[idx] = z;
                }
            }
            __syncthreads();
            float acc0[8], acc1[8];
            #pragma unroll
            for (int i = 0; i < 8; i++) { acc0[i] = 0.f; acc1[i] = 0.f; }
            #pragma unroll
            for (int i = 0; i < 8; i++) {
                const float4* xrow = hl4 + (bh * 8 + i) * LSTRIDE + ks;
                const float4* hrow = hl24 + (bh * 8 + i) * LSTRIDE + ks;
                #pragma unroll
                for (int pp = 0; pp < 8; pp++) {
                    float4 x4 = xrow[pp * 17];
                    acc0[i] = fmaf(x4.x, wx0[pp*4+0], acc0[i]);
                    acc1[i] = fmaf(x4.x, wx1[pp*4+0], acc1[i]);
                    acc0[i] = fmaf(x4.y, wx0[pp*4+1], acc0[i]);
                    acc1[i] = fmaf(x4.y, wx1[pp*4+1], acc1[i]);
                    acc0[i] = fmaf(x4.z, wx0[pp*4+2], acc0[i]);
                    acc1[i] = fmaf(x4.z, wx1[pp*4+2], acc1[i]);
                    acc0[i] = fmaf(x4.w, wx0[pp*4+3], acc0[i]);
                    acc1[i] = fmaf(x4.w, wx1[pp*4+3], acc1[i]);
                }
                #pragma unroll
                for (int pp = 0; pp < 8; pp++) {
                    float4 h4 = hrow[pp * 17];
                    acc0[i] = fmaf(h4.x, wh0[pp*4+0], acc0[i]);
                    acc1[i] = fmaf(h4.x, wh1r[pp*4+0], acc1[i]);
                    acc0[i] = fmaf(h4.y, wh0[pp*4+1], acc0[i]);
                    acc1[i] = fmaf(h4.y, wh1r[pp*4+1], acc1[i]);
                    acc0[i] = fmaf(h4.z, wh0[pp*4+2], acc0[i]);
                    acc1[i] = fmaf(h4.z, wh1r[pp*4+2], acc1[i]);
                    acc0[i] = fmaf(h4.w, wh0[pp*4+3], acc0[i]);
                    acc1[i] = fmaf(h4.w, wh1r[pp*4+3], acc1[i]);
                }
            }
            #pragma unroll
            for (int i = 0; i < 8; i++) {
                part[ks * 256 + c0 * 16 + bh * 8 + i]       = acc0[i];
                part[ks * 256 + (c0 + 1) * 16 + bh * 8 + i] = acc1[i];
            }
            __syncthreads();
            float gv = bias2v;
            #pragma unroll
            for (int k = 0; k < 16; k++)
                gv += part[k * 256 + cl_r * 16 + b_r];
            gl[cl_r * 16 + b_r] = gv;
            __syncthreads();
            if (t < 64) {
                int b = t >> 2, jr = t & 3;
                float iv = gl[(0 + jr) * 16 + b];
                float fv = gl[(4 + jr) * 16 + b];
                float gg = gl[(8 + jr) * 16 + b];
                float ov = gl[(12 + jr) * 16 + b];
                float ig = 1.f / (1.f + expf(-iv));
                float fg = 1.f / (1.f + expf(-fv));
                float og = 1.f / (1.f + expf(-ov));
                float cn = fg * c_lds[t] + ig * tanhf(gg);
                float hn = og * tanhf(cn);
                c_lds[t] = cn;
                int j = j_base + jr;
                __hip_atomic_store(&h2hist[(size_t)m * 8192 + bid * 64 + t], hn,
                                   __ATOMIC_RELAXED, __HIP_MEMORY_SCOPE_AGENT);
                H2out[(size_t)(b * 512 + m) * 512 + j] = hn;   // normal cached store
            }
            wait_vm0();
            if (t == 0)
                __hip_atomic_store(&slots1[bid * SLOT_STRIDE], (unsigned)(m + 1),
                                   __ATOMIC_RELAXED, __HIP_MEMORY_SCOPE_AGENT);
        }
    }
}

__global__ void finalize_loss_kernel(const float* __restrict__ acc, float* __restrict__ out)
{
    int q = threadIdx.x;
    if (q < 4) out[2621440 + q] = acc[q] * (1.f / 4194304.f);
}

extern "C" void kernel_launch(void* const* d_in, const int* in_sizes, int n_in,
                              void* d_out, int out_size, void* d_ws, size_t ws_size,
                              hipStream_t stream)
{
    const float* waveform  = (const float*)d_in[0];
    const float* enc_w     = (const float*)d_in[1];
    const float* enc_b     = (const float*)d_in[2];
    const float* ln_g      = (const float*)d_in[3];
    const float* ln_b      = (const float*)d_in[4];
    const float* codebooks = (const float*)d_in[5];
    const float* lstm_wi   = (const float*)d_in[6];
    const float* lstm_wh   = (const float*)d_in[7];
    const float* lstm_bi   = (const float*)d_in[8];
    const float* lstm_bh   = (const float*)d_in[9];
    const float* dec_w     = (const float*)d_in[10];
    const float* dec_b     = (const float*)d_in[11];
    float* out = (float*)d_out;

    float* ws = (float*)d_ws;                  // float offsets
    float* residual = ws;                      // 4,194,304 (later: h2 history)
    float* quant    = ws + 4194304;            // 4,194,304 (permuted; later h1 history)
    float* H2       = ws + 8388608;            // 4,194,304
    float* big      = ws + 12582912;           // 16,777,216 (VQ D, then LSTM P1)
    unsigned* slots = (unsigned*)(ws + 29360128); // 2 roles x 128 x 16 u32 = 16 KB
    float* norms    = ws + 29392896;           // 4096
    float* loss_acc = ws + 29396992;           // 16

    hipMemsetAsync(loss_acc, 0, 16 * sizeof(float), stream);
    hipMemsetAsync(slots, 0, 4096 * sizeof(unsigned), stream);

    // Encoder
    gemm64<false><<<dim3(8, 128), 256, 0, stream>>>(waveform, enc_w, residual,
                                                    8192, 512, 320, enc_b, nullptr);
    ln_relu_kernel<<<8192, 256, 0, stream>>>(residual, ln_g, ln_b);

    // Residual VQ
    rownorm_kernel<<<4096, 256, 0, stream>>>(codebooks, norms);
    for (int q = 0; q < 4; q++) {
        const float* cb = codebooks + (size_t)q * 1024 * 512;
        gemm128<true><<<dim3(8, 64), 256, 0, stream>>>(residual, cb, big,
                                                       8192, 1024, 512, nullptr, nullptr);
        vq_update_kernel<<<8192, 256, 0, stream>>>(big, norms + q * 1024, cb,
                                                   residual, quant, loss_acc + q, q == 0);
    }

    // P1 = quant(permuted) @ wi1^T + bi1 + bh1 -> step-major rows m' = s*16 + b
    gemm128<true><<<dim3(16, 64), 256, 0, stream>>>(quant, lstm_wi, big,
                                                    8192, 2048, 512, lstm_bi, lstm_bh);
    // Fused 2-layer LSTM
    lstm_fused_kernel<<<dim3(256), dim3(256), 0, stream>>>(
        big, lstm_wh, lstm_wi + (size_t)2048 * 512, lstm_wh + (size_t)2048 * 512,
        lstm_bi + 2048, lstm_bh + 2048, H2, quant, residual, slots);

    // Decoder -> d_out
    gemm64<false><<<dim3(5, 128), 256, 0, stream>>>(H2, dec_w, out,
                                                    8192, 320, 512, dec_b, nullptr);
    finalize_loss_kernel<<<1, 4, 0, stream>>>(loss_acc, out);
}

// Round 9
// 4468.661 us; speedup vs baseline: 1.6186x; 1.6186x over previous
//
#include <hip/hip_runtime.h>
#include <cmath>

// Problem constants: B=16, T=512, S=320, H=512, K=1024, NQ=4, M=B*T=8192

// ---------------- generic 64x64 tile f32 GEMM (decoder N=320) ----------------
template<bool BT>
__global__ __launch_bounds__(256)
void gemm64(const float* __restrict__ A, const float* __restrict__ B,
            float* __restrict__ C, int M, int N, int K,
            const float* __restrict__ bias1, const float* __restrict__ bias2)
{
    __shared__ float Al[32][68];
    __shared__ float Bl[32][68];
    const int m0 = blockIdx.y * 64, n0 = blockIdx.x * 64;
    const int t = threadIdx.x;
    const int tm = t >> 4, tn = t & 15;
    float acc[4][4] = {{0.f, 0.f, 0.f, 0.f}};

    for (int k0 = 0; k0 < K; k0 += 32) {
        #pragma unroll
        for (int i = 0; i < 2; i++) {
            int f4 = t + i * 256;
            int row = f4 >> 3, c4 = f4 & 7;
            float4 v = *(const float4*)(A + (size_t)(m0 + row) * K + k0 + c4 * 4);
            Al[c4*4+0][row] = v.x; Al[c4*4+1][row] = v.y;
            Al[c4*4+2][row] = v.z; Al[c4*4+3][row] = v.w;
        }
        if (BT) {
            #pragma unroll
            for (int i = 0; i < 2; i++) {
                int f4 = t + i * 256;
                int row = f4 >> 3, c4 = f4 & 7;
                float4 v = *(const float4*)(B + (size_t)(n0 + row) * K + k0 + c4 * 4);
                Bl[c4*4+0][row] = v.x; Bl[c4*4+1][row] = v.y;
                Bl[c4*4+2][row] = v.z; Bl[c4*4+3][row] = v.w;
            }
        } else {
            #pragma unroll
            for (int i = 0; i < 2; i++) {
                int f4 = t + i * 256;
                int kk = f4 >> 4, c4 = f4 & 15;
                float4 v = *(const float4*)(B + (size_t)(k0 + kk) * N + n0 + c4 * 4);
                *(float4*)&Bl[kk][c4 * 4] = v;
            }
        }
        __syncthreads();
        #pragma unroll
        for (int k = 0; k < 32; k++) {
            float4 a4 = *(const float4*)&Al[k][tm * 4];
            float4 b4 = *(const float4*)&Bl[k][tn * 4];
            float av[4] = {a4.x, a4.y, a4.z, a4.w};
            float bv[4] = {b4.x, b4.y, b4.z, b4.w};
            #pragma unroll
            for (int i = 0; i < 4; i++)
                #pragma unroll
                for (int j = 0; j < 4; j++)
                    acc[i][j] = fmaf(av[i], bv[j], acc[i][j]);
        }
        __syncthreads();
    }
    float bn[4];
    #pragma unroll
    for (int j = 0; j < 4; j++) {
        float bb = 0.f;
        if (bias1) bb += bias1[n0 + tn * 4 + j];
        if (bias2) bb += bias2[n0 + tn * 4 + j];
        bn[j] = bb;
    }
    #pragma unroll
    for (int i = 0; i < 4; i++) {
        float4 o;
        o.x = acc[i][0] + bn[0]; o.y = acc[i][1] + bn[1];
        o.z = acc[i][2] + bn[2]; o.w = acc[i][3] + bn[3];
        *(float4*)(C + (size_t)(m0 + tm * 4 + i) * N + n0 + tn * 4) = o;
    }
}

// ---------------- 128x128 tile f32 GEMM, 8x8 acc (encoder, VQ, P1) ----------------
template<bool BT>
__global__ __launch_bounds__(256)
void gemm128(const float* __restrict__ A, const float* __restrict__ B,
             float* __restrict__ C, int M, int N, int K,
             const float* __restrict__ bias1, const float* __restrict__ bias2)
{
    __shared__ float Al[16][132];
    __shared__ float Bl[16][132];
    const int m0 = blockIdx.y * 128, n0 = blockIdx.x * 128;
    const int t = threadIdx.x;
    const int tm = t >> 4, tn = t & 15;
    float acc[8][8] = {};

    for (int k0 = 0; k0 < K; k0 += 16) {
        #pragma unroll
        for (int i = 0; i < 2; i++) {
            int f4 = t + i * 256;              // 0..511
            int row = f4 >> 2, c4 = f4 & 3;
            float4 v = *(const float4*)(A + (size_t)(m0 + row) * K + k0 + c4 * 4);
            Al[c4*4+0][row] = v.x; Al[c4*4+1][row] = v.y;
            Al[c4*4+2][row] = v.z; Al[c4*4+3][row] = v.w;
        }
        if (BT) {
            #pragma unroll
            for (int i = 0; i < 2; i++) {
                int f4 = t + i * 256;
                int row = f4 >> 2, c4 = f4 & 3;
                float4 v = *(const float4*)(B + (size_t)(n0 + row) * K + k0 + c4 * 4);
                Bl[c4*4+0][row] = v.x; Bl[c4*4+1][row] = v.y;
                Bl[c4*4+2][row] = v.z; Bl[c4*4+3][row] = v.w;
            }
        } else {
            #pragma unroll
            for (int i = 0; i < 2; i++) {
                int f4 = t + i * 256;
                int kk = f4 >> 5, c4 = f4 & 31;
                float4 v = *(const float4*)(B + (size_t)(k0 + kk) * N + n0 + c4 * 4);
                *(float4*)&Bl[kk][c4 * 4] = v;
            }
        }
        __syncthreads();
        #pragma unroll
        for (int k = 0; k < 16; k++) {
            float4 a0 = *(const float4*)&Al[k][tm * 8];
            float4 a1 = *(const float4*)&Al[k][tm * 8 + 4];
            float4 b0 = *(const float4*)&Bl[k][tn * 8];
            float4 b1 = *(const float4*)&Bl[k][tn * 8 + 4];
            float av[8] = {a0.x,a0.y,a0.z,a0.w,a1.x,a1.y,a1.z,a1.w};
            float bv[8] = {b0.x,b0.y,b0.z,b0.w,b1.x,b1.y,b1.z,b1.w};
            #pragma unroll
            for (int i = 0; i < 8; i++)
                #pragma unroll
                for (int j = 0; j < 8; j++)
                    acc[i][j] = fmaf(av[i], bv[j], acc[i][j]);
        }
        __syncthreads();
    }
    float bn[8];
    #pragma unroll
    for (int j = 0; j < 8; j++) {
        float bb = 0.f;
        if (bias1) bb += bias1[n0 + tn * 8 + j];
        if (bias2) bb += bias2[n0 + tn * 8 + j];
        bn[j] = bb;
    }
    #pragma unroll
    for (int i = 0; i < 8; i++) {
        float* cp = C + (size_t)(m0 + tm * 8 + i) * N + n0 + tn * 8;
        float4 o0, o1;
        o0.x = acc[i][0]+bn[0]; o0.y = acc[i][1]+bn[1];
        o0.z = acc[i][2]+bn[2]; o0.w = acc[i][3]+bn[3];
        o1.x = acc[i][4]+bn[4]; o1.y = acc[i][5]+bn[5];
        o1.z = acc[i][6]+bn[6]; o1.w = acc[i][7]+bn[7];
        *(float4*)cp = o0;
        *(float4*)(cp + 4) = o1;
    }
}

// ---------------- LayerNorm + ReLU in place ----------------
__global__ __launch_bounds__(256)
void ln_relu_kernel(float* __restrict__ X, const float* __restrict__ g,
                    const float* __restrict__ bb)
{
    __shared__ float red[256];
    __shared__ float stat[2];
    const int row = blockIdx.x, t = threadIdx.x;
    float x0 = X[(size_t)row * 512 + t];
    float x1 = X[(size_t)row * 512 + 256 + t];
    red[t] = x0 + x1;
    __syncthreads();
    for (int o = 128; o > 0; o >>= 1) { if (t < o) red[t] += red[t + o]; __syncthreads(); }
    if (t == 0) stat[0] = red[0] * (1.f / 512.f);
    __syncthreads();
    float mu = stat[0];
    float d0 = x0 - mu, d1 = x1 - mu;
    red[t] = d0 * d0 + d1 * d1;
    __syncthreads();
    for (int o = 128; o > 0; o >>= 1) { if (t < o) red[t] += red[t + o]; __syncthreads(); }
    if (t == 0) stat[1] = red[0] * (1.f / 512.f);
    __syncthreads();
    float rs = rsqrtf(stat[1] + 1e-5f);
    float y0 = d0 * rs * g[t] + bb[t];
    float y1 = d1 * rs * g[256 + t] + bb[256 + t];
    X[(size_t)row * 512 + t] = fmaxf(y0, 0.f);
    X[(size_t)row * 512 + 256 + t] = fmaxf(y1, 0.f);
}

// ---------------- codebook row squared-norms ----------------
__global__ __launch_bounds__(256)
void rownorm_kernel(const float* __restrict__ Ein, float* __restrict__ norms)
{
    __shared__ float red[256];
    const int row = blockIdx.x, t = threadIdx.x;
    float a = Ein[(size_t)row * 512 + t];
    float b = Ein[(size_t)row * 512 + 256 + t];
    red[t] = a * a + b * b;
    __syncthreads();
    for (int o = 128; o > 0; o >>= 1) { if (t < o) red[t] += red[t + o]; __syncthreads(); }
    if (t == 0) norms[row] = red[0];
}

// ---------------- VQ argmin + STE update ----------------
// quant written ROW-PERMUTED (tokP = s*16 + b) so the P1 GEMM produces P1 in
// step-major layout (row m' = s*16 + b); LSTM reads contiguous per-step windows.
__global__ __launch_bounds__(256)
void vq_update_kernel(const float* __restrict__ D, const float* __restrict__ norms,
                      const float* __restrict__ cb, float* __restrict__ residual,
                      float* __restrict__ quant, float* __restrict__ loss_acc,
                      int first)
{
    __shared__ unsigned long long red[256];
    __shared__ float fred[256];
    __shared__ int sidx;
    __shared__ float sdmin;
    const int tok = blockIdx.x, t = threadIdx.x;
    unsigned long long best = ~0ull;
    #pragma unroll
    for (int i = 0; i < 4; i++) {
        int k = t + i * 256;
        float d = fmaf(-2.f, D[(size_t)tok * 1024 + k], norms[k]);
        unsigned u = __float_as_uint(d);
        u = (u & 0x80000000u) ? ~u : (u | 0x80000000u);
        unsigned long long p = ((unsigned long long)u << 32) | (unsigned)k;
        best = p < best ? p : best;
    }
    red[t] = best;
    __syncthreads();
    for (int o = 128; o > 0; o >>= 1) {
        if (t < o) red[t] = red[t + o] < red[t] ? red[t + o] : red[t];
        __syncthreads();
    }
    if (t == 0) {
        unsigned long long r0 = red[0];
        sidx = (int)(r0 & 0xffffffffu);
        unsigned uv = (unsigned)(r0 >> 32);
        unsigned orig = (uv & 0x80000000u) ? (uv ^ 0x80000000u) : ~uv;
        sdmin = __uint_as_float(orig);
    }
    float r0v = residual[(size_t)tok * 512 + t];
    float r1v = residual[(size_t)tok * 512 + 256 + t];
    fred[t] = r0v * r0v + r1v * r1v;
    __syncthreads();
    for (int o = 128; o > 0; o >>= 1) { if (t < o) fred[t] += fred[t + o]; __syncthreads(); }
    int idx = sidx;
    if (t == 0) atomicAdd(loss_acc, sdmin + fred[0]);
    const float* E = cb + (size_t)idx * 512;
    float e0 = E[t], e1 = E[256 + t];
    float q0 = r0v + (e0 - r0v);
    float q1 = r1v + (e1 - r1v);
    residual[(size_t)tok * 512 + t]       = r0v - q0;
    residual[(size_t)tok * 512 + 256 + t] = r1v - q1;
    const int tokP = ((tok & 511) << 4) | (tok >> 9);   // s*16 + b
    if (first) {
        quant[(size_t)tokP * 512 + t]       = q0;
        quant[(size_t)tokP * 512 + 256 + t] = q1;
    } else {
        quant[(size_t)tokP * 512 + t]       += q0;
        quant[(size_t)tokP * 512 + 256 + t] += q1;
    }
}

// ================= fused 2-layer LSTM ==============================================
// R9 (measured R8: VGPR 256 + 8-way part-write conflicts confounded the
// read-halving test). Clean retest: k-split 32, thread=(ks 0..31, q 0..7)
// covers 2 adjacent cols x 16-k slice. Weight regs = R7's (32/64 floats).
// Dot reads: role-0 64/thread (was 128), role-1 128 (was 256); each b128 read
// feeds 8 FMAs. part[32][c*17+b] stride 271: write ~2-3way, reduce ~2way.
// Dot reads conflict-free under the R7 swizzle (8 ks -> addr4 mod 8 distinct).

#define LSTRIDE 137          // float4 stride per sample row in LDS (16 rows)
#define SLOT_STRIDE 16       // u32 stride between slots = 64B = 1 line
#define PART_SK 271          // float stride per k-slice in part[]

__device__ __forceinline__ int sw(int blk) { return (blk & 7) * 17 + (blk >> 3); }

__device__ __forceinline__ void wait_vm0() {
    asm volatile("s_waitcnt vmcnt(0)" ::: "memory");
}

__device__ __forceinline__ void ld4_issue(float4& a, float4& b, float4& c, float4& d,
                                          const float4* p0, const float4* p1,
                                          const float4* p2, const float4* p3)
{
    asm volatile(
        "global_load_dwordx4 %0, %4, off sc0 sc1\n\t"
        "global_load_dwordx4 %1, %5, off sc0 sc1\n\t"
        "global_load_dwordx4 %2, %6, off sc0 sc1\n\t"
        "global_load_dwordx4 %3, %7, off sc0 sc1"
        : "=&v"(a), "=&v"(b), "=&v"(c), "=&v"(d)
        : "v"(p0), "v"(p1), "v"(p2), "v"(p3)
        : "memory");
}

// stage 32KB block-major global h -> transposed/swizzled LDS, ONE drain
__device__ __forceinline__ void stage8t(float4* d4, const float* src, int t)
{
    const float4* s4 = (const float4*)src;
    float4 v[8];
    ld4_issue(v[0], v[1], v[2], v[3], s4 + t, s4 + t + 256, s4 + t + 512, s4 + t + 768);
    ld4_issue(v[4], v[5], v[6], v[7], s4 + t + 1024, s4 + t + 1280, s4 + t + 1536, s4 + t + 1792);
    wait_vm0();
    #pragma unroll
    for (int i = 0; i < 8; i++) {
        int G = t + i * 256;
        int b = G & 15, blk = G >> 4;
        d4[b * LSTRIDE + sw(blk)] = v[i];
    }
}

// stage 2x32KB with 16 loads in flight, ONE drain (role-1 x + h)
__device__ __forceinline__ void stage16t(float4* d1, const float* src1,
                                         float4* d2, const float* src2, int t)
{
    const float4* s1 = (const float4*)src1;
    const float4* s2 = (const float4*)src2;
    float4 v[16];
    ld4_issue(v[0], v[1], v[2], v[3],  s1 + t, s1 + t + 256, s1 + t + 512, s1 + t + 768);
    ld4_issue(v[4], v[5], v[6], v[7],  s1 + t + 1024, s1 + t + 1280, s1 + t + 1536, s1 + t + 1792);
    ld4_issue(v[8], v[9], v[10],v[11], s2 + t, s2 + t + 256, s2 + t + 512, s2 + t + 768);
    ld4_issue(v[12],v[13],v[14],v[15], s2 + t + 1024, s2 + t + 1280, s2 + t + 1536, s2 + t + 1792);
    wait_vm0();
    #pragma unroll
    for (int i = 0; i < 8; i++) {
        int G = t + i * 256;
        int b = G & 15, blk = G >> 4;
        int idx = b * LSTRIDE + sw(blk);
        d1[idx] = v[i];
        d2[idx] = v[i + 8];
    }
}

__device__ __forceinline__ unsigned slot_load(const unsigned* p)
{
    return __hip_atomic_load(p, __ATOMIC_RELAXED, __HIP_MEMORY_SCOPE_AGENT);
}

// one wave checks all 128 slots (2 loads/lane)
__device__ __forceinline__ void poll128(const unsigned* slots, int lane, unsigned tgt)
{
    const unsigned* p0 = slots + (size_t)lane * SLOT_STRIDE;
    const unsigned* p1 = slots + (size_t)(64 + lane) * SLOT_STRIDE;
    int spins = 0;
    while (true) {
        unsigned a = slot_load(p0);
        unsigned b = slot_load(p1);
        if (__all(a >= tgt && b >= tgt)) break;
        __builtin_amdgcn_s_sleep(2);
        if (++spins > 300000) break;   // bounded: never hang
    }
}

__global__ __launch_bounds__(256, 1)
void lstm_fused_kernel(const float* __restrict__ P1,   // step-major rows: m' = s*16+b
                       const float* __restrict__ wh1,
                       const float* __restrict__ wi2,
                       const float* __restrict__ wh2,
                       const float* __restrict__ bi2,
                       const float* __restrict__ bh2,
                       float* __restrict__ H2out,
                       float* __restrict__ h1hist,   // [step][block][64]
                       float* __restrict__ h2hist,   // [step][block][64]
                       unsigned* __restrict__ slots)
{
    __shared__ float4 hl4[16 * LSTRIDE];   // 34.25 KB x-staging (swizzled)
    __shared__ float4 hl24[16 * LSTRIDE];  // 34.25 KB h-staging (role 1)
    __shared__ float part[32 * PART_SK];   // 34.7 KB partials
    __shared__ float gl[256];
    __shared__ float c_lds[64];

    const int t = threadIdx.x;
    const int role = blockIdx.x >> 7;
    const int bid = blockIdx.x & 127;
    const int ks = t >> 3;                 // 0..31 k-slice (16 k each)
    const int q  = t & 7;                  // 0..7 column-pair
    const int c0 = q * 2;                  // block-local cols c0, c0+1
    const int j_base = bid * 4;
    const int cl_r = t >> 4, b_r = t & 15;
    const int gate_r = cl_r >> 2, jj_r = cl_r & 3;
    const int w = t >> 6, lane = t & 63;

    unsigned* slots0 = slots;
    unsigned* slots1 = slots + 128 * SLOT_STRIDE;

    // weights for the two adjacent columns (same gate since c0 even), 16-k slice
    float wh0[16], wh1r[16], wx0[16], wx1[16];
    {
        const float* whp = (role == 0) ? wh1 : wh2;
        const int gate0 = c0 >> 2, jj0 = c0 & 3;
        const float* wr = whp + (size_t)(gate0 * 512 + j_base + jj0) * 512 + ks * 16;
        #pragma unroll
        for (int i = 0; i < 16; i++) { wh0[i] = wr[i]; wh1r[i] = wr[512 + i]; }
    }
    if (role == 1) {
        const int gate0 = c0 >> 2, jj0 = c0 & 3;
        const float* wr = wi2 + (size_t)(gate0 * 512 + j_base + jj0) * 512 + ks * 16;
        #pragma unroll
        for (int i = 0; i < 16; i++) { wx0[i] = wr[i]; wx1[i] = wr[512 + i]; }
    } else {
        #pragma unroll
        for (int i = 0; i < 16; i++) { wx0[i] = 0.f; wx1[i] = 0.f; }
    }
    float bias2v = 0.f;
    if (role == 1) {
        int col = gate_r * 512 + j_base + jj_r;
        bias2v = bi2[col] + bh2[col];
    }
    if (t < 64) c_lds[t] = 0.f;

    if (role == 0) {
        // -------- layer 1: 128 blocks, peer slot-barrier only (wave 0 polls)
        const float* pvp = P1 + (size_t)b_r * 2048 + gate_r * 512 + j_base + jj_r;
        float pv = pvp[0];                       // step 0 row = 0*16 + b_r
        for (int s = 0; s < 512; s++) {
            if (w == 0) poll128(slots0, lane, (unsigned)s);
            __syncthreads();
            if (s > 0) {
                stage8t(hl4, h1hist + (size_t)(s - 1) * 8192, t);
            } else {
                float4 z = make_float4(0.f, 0.f, 0.f, 0.f);
                #pragma unroll
                for (int i = 0; i < 9; i++) {
                    int idx = t + i * 256;
                    if (idx < 16 * LSTRIDE) hl4[idx] = z;
                }
            }
            float pv_next = (s < 511) ? pvp[(size_t)(s + 1) * 32768] : 0.f;
            __syncthreads();
            float acc0[16], acc1[16];
            #pragma unroll
            for (int b = 0; b < 16; b++) { acc0[b] = 0.f; acc1[b] = 0.f; }
            #pragma unroll
            for (int b = 0; b < 16; b++) {
                const float4* hrow = hl4 + b * LSTRIDE;
                #pragma unroll
                for (int j4 = 0; j4 < 4; j4++) {
                    float4 h4 = hrow[sw(ks * 4 + j4)];
                    acc0[b] = fmaf(h4.x, wh0[j4*4+0], acc0[b]);
                    acc1[b] = fmaf(h4.x, wh1r[j4*4+0], acc1[b]);
                    acc0[b] = fmaf(h4.y, wh0[j4*4+1], acc0[b]);
                    acc1[b] = fmaf(h4.y, wh1r[j4*4+1], acc1[b]);
                    acc0[b] = fmaf(h4.z, wh0[j4*4+2], acc0[b]);
                    acc1[b] = fmaf(h4.z, wh1r[j4*4+2], acc1[b]);
                    acc0[b] = fmaf(h4.w, wh0[j4*4+3], acc0[b]);
                    acc1[b] = fmaf(h4.w, wh1r[j4*4+3], acc1[b]);
                }
            }
            #pragma unroll
            for (int b = 0; b < 16; b++) {
                part[ks * PART_SK + c0 * 17 + b]       = acc0[b];
                part[ks * PART_SK + (c0 + 1) * 17 + b] = acc1[b];
            }
            __syncthreads();
            float gv = pv;
            #pragma unroll
            for (int k = 0; k < 32; k++)
                gv += part[k * PART_SK + cl_r * 17 + b_r];
            gl[cl_r * 16 + b_r] = gv;
            __syncthreads();
            if (t < 64) {
                int b = t >> 2, jr = t & 3;
                float iv = gl[(0 + jr) * 16 + b];
                float fv = gl[(4 + jr) * 16 + b];
                float gg = gl[(8 + jr) * 16 + b];
                float ov = gl[(12 + jr) * 16 + b];
                float ig = 1.f / (1.f + expf(-iv));
                float fg = 1.f / (1.f + expf(-fv));
                float og = 1.f / (1.f + expf(-ov));
                float cn = fg * c_lds[t] + ig * tanhf(gg);
                float hn = og * tanhf(cn);
                c_lds[t] = cn;
                __hip_atomic_store(&h1hist[(size_t)s * 8192 + bid * 64 + t], hn,
                                   __ATOMIC_RELAXED, __HIP_MEMORY_SCOPE_AGENT);
            }
            wait_vm0();                 // t==0 is in wave 0: drains all t<64 stores
            if (t == 0)
                __hip_atomic_store(&slots0[bid * SLOT_STRIDE], (unsigned)(s + 1),
                                   __ATOMIC_RELAXED, __HIP_MEMORY_SCOPE_AGENT);
            pv = pv_next;
        }
    } else {
        // -------- layer 2: wave0 polls h1-ready, wave1 polls peers-done, concurrently
        for (int m = 0; m < 512; m++) {
            if (w == 0)      poll128(slots0, lane, (unsigned)(m + 1));
            else if (w == 1) poll128(slots1, lane, (unsigned)m);
            __syncthreads();
            if (m > 0) {
                stage16t(hl4, h1hist + (size_t)m * 8192,
                         hl24, h2hist + (size_t)(m - 1) * 8192, t);
            } else {
                stage8t(hl4, h1hist, t);
                float4 z = make_float4(0.f, 0.f, 0.f, 0.f);
                #pragma unroll
                for (int i = 0; i < 9; i++) {
                    int idx = t + i * 256;
                    if (idx < 16 * LSTRIDE) hl24[idx] = z;
                }
            }
            __syncthreads();
            float acc0[16], acc1[16];
            #pragma unroll
            for (int b = 0; b < 16; b++) { acc0[b] = 0.f; acc1[b] = 0.f; }
            #pragma unroll
            for (int b = 0; b < 16; b++) {
                const float4* xrow = hl4 + b * LSTRIDE;
                const float4* hrow = hl24 + b * LSTRIDE;
                #pragma unroll
                for (int j4 = 0; j4 < 4; j4++) {
                    float4 x4 = xrow[sw(ks * 4 + j4)];
                    acc0[b] = fmaf(x4.x, wx0[j4*4+0], acc0[b]);
                    acc1[b] = fmaf(x4.x, wx1[j4*4+0], acc1[b]);
                    acc0[b] = fmaf(x4.y, wx0[j4*4+1], acc0[b]);
                    acc1[b] = fmaf(x4.y, wx1[j4*4+1], acc1[b]);
                    acc0[b] = fmaf(x4.z, wx0[j4*4+2], acc0[b]);
                    acc1[b] = fmaf(x4.z, wx1[j4*4+2], acc1[b]);
                    acc0[b] = fmaf(x4.w, wx0[j4*4+3], acc0[b]);
                    acc1[b] = fmaf(x4.w, wx1[j4*4+3], acc1[b]);
                }
                #pragma unroll
                for (int j4 = 0; j4 < 4; j4++) {
                    float4 h4 = hrow[sw(ks * 4 + j4)];
                    acc0[b] = fmaf(h4.x, wh0[j4*4+0], acc0[b]);
                    acc1[b] = fmaf(h4.x, wh1r[j4*4+0], acc1[b]);
                    acc0[b] = fmaf(h4.y, wh0[j4*4+1], acc0[b]);
                    acc1[b] = fmaf(h4.y, wh1r[j4*4+1], acc1[b]);
                    acc0[b] = fmaf(h4.z, wh0[j4*4+2], acc0[b]);
                    acc1[b] = fmaf(h4.z, wh1r[j4*4+2], acc1[b]);
                    acc0[b] = fmaf(h4.w, wh0[j4*4+3], acc0[b]);
                    acc1[b] = fmaf(h4.w, wh1r[j4*4+3], acc1[b]);
                }
            }
            #pragma unroll
            for (int b = 0; b < 16; b++) {
                part[ks * PART_SK + c0 * 17 + b]       = acc0[b];
                part[ks * PART_SK + (c0 + 1) * 17 + b] = acc1[b];
            }
            __syncthreads();
            float gv = bias2v;
            #pragma unroll
            for (int k = 0; k < 32; k++)
                gv += part[k * PART_SK + cl_r * 17 + b_r];
            gl[cl_r * 16 + b_r] = gv;
            __syncthreads();
            if (t < 64) {
                int b = t >> 2, jr = t & 3;
                float iv = gl[(0 + jr) * 16 + b];
                float fv = gl[(4 + jr) * 16 + b];
                float gg = gl[(8 + jr) * 16 + b];
                float ov = gl[(12 + jr) * 16 + b];
                float ig = 1.f / (1.f + expf(-iv));
                float fg = 1.f / (1.f + expf(-fv));
                float og = 1.f / (1.f + expf(-ov));
                float cn = fg * c_lds[t] + ig * tanhf(gg);
                float hn = og * tanhf(cn);
                c_lds[t] = cn;
                int j = j_base + jr;
                __hip_atomic_store(&h2hist[(size_t)m * 8192 + bid * 64 + t], hn,
                                   __ATOMIC_RELAXED, __HIP_MEMORY_SCOPE_AGENT);
                H2out[(size_t)(b * 512 + m) * 512 + j] = hn;   // normal cached store
            }
            wait_vm0();
            if (t == 0)
                __hip_atomic_store(&slots1[bid * SLOT_STRIDE], (unsigned)(m + 1),
                                   __ATOMIC_RELAXED, __HIP_MEMORY_SCOPE_AGENT);
        }
    }
}

__global__ void finalize_loss_kernel(const float* __restrict__ acc, float* __restrict__ out)
{
    int q = threadIdx.x;
    if (q < 4) out[2621440 + q] = acc[q] * (1.f / 4194304.f);
}

extern "C" void kernel_launch(void* const* d_in, const int* in_sizes, int n_in,
                              void* d_out, int out_size, void* d_ws, size_t ws_size,
                              hipStream_t stream)
{
    const float* waveform  = (const float*)d_in[0];
    const float* enc_w     = (const float*)d_in[1];
    const float* enc_b     = (const float*)d_in[2];
    const float* ln_g      = (const float*)d_in[3];
    const float* ln_b      = (const float*)d_in[4];
    const float* codebooks = (const float*)d_in[5];
    const float* lstm_wi   = (const float*)d_in[6];
    const float* lstm_wh   = (const float*)d_in[7];
    const float* lstm_bi   = (const float*)d_in[8];
    const float* lstm_bh   = (const float*)d_in[9];
    const float* dec_w     = (const float*)d_in[10];
    const float* dec_b     = (const float*)d_in[11];
    float* out = (float*)d_out;

    float* ws = (float*)d_ws;                  // float offsets
    float* residual = ws;                      // 4,194,304 (later: h2 history)
    float* quant    = ws + 4194304;            // 4,194,304 (permuted; later h1 history)
    float* H2       = ws + 8388608;            // 4,194,304
    float* big      = ws + 12582912;           // 16,777,216 (VQ D, then LSTM P1)
    unsigned* slots = (unsigned*)(ws + 29360128); // 2 roles x 128 x 16 u32 = 16 KB
    float* norms    = ws + 29392896;           // 4096
    float* loss_acc = ws + 29396992;           // 16

    hipMemsetAsync(loss_acc, 0, 16 * sizeof(float), stream);
    hipMemsetAsync(slots, 0, 4096 * sizeof(unsigned), stream);

    // Encoder (now gemm128: M=8192, N=512, K=320 all divisible)
    gemm128<false><<<dim3(4, 64), 256, 0, stream>>>(waveform, enc_w, residual,
                                                    8192, 512, 320, enc_b, nullptr);
    ln_relu_kernel<<<8192, 256, 0, stream>>>(residual, ln_g, ln_b);

    // Residual VQ
    rownorm_kernel<<<4096, 256, 0, stream>>>(codebooks, norms);
    for (int q = 0; q < 4; q++) {
        const float* cb = codebooks + (size_t)q * 1024 * 512;
        gemm128<true><<<dim3(8, 64), 256, 0, stream>>>(residual, cb, big,
                                                       8192, 1024, 512, nullptr, nullptr);
        vq_update_kernel<<<8192, 256, 0, stream>>>(big, norms + q * 1024, cb,
                                                   residual, quant, loss_acc + q, q == 0);
    }

    // P1 = quant(permuted) @ wi1^T + bi1 + bh1 -> step-major rows m' = s*16 + b
    gemm128<true><<<dim3(16, 64), 256, 0, stream>>>(quant, lstm_wi, big,
                                                    8192, 2048, 512, lstm_bi, lstm_bh);
    // Fused 2-layer LSTM
    lstm_fused_kernel<<<dim3(256), dim3(256), 0, stream>>>(
        big, lstm_wh, lstm_wi + (size_t)2048 * 512, lstm_wh + (size_t)2048 * 512,
        lstm_bi + 2048, lstm_bh + 2048, H2, quant, residual, slots);

    // Decoder -> d_out
    gemm64<false><<<dim3(5, 128), 256, 0, stream>>>(H2, dec_w, out,
                                                    8192, 320, 512, dec_b, nullptr);
    finalize_loss_kernel<<<1, 4, 0, stream>>>(loss_acc, out);
}